// Round 2
// 426.022 us; speedup vs baseline: 1.1266x; 1.1266x over previous
//
#include <hip/hip_runtime.h>
#include <stdint.h>

// ---------------------------------------------------------------------------
// E8RHT MLP:  out = ( gelu( rht(x) @ Wup^T ) -> rht -> @ Wdn^T )
// Folded: W_eff[o,:] = signs * blockwise-FWHT(wq[o,:]) * scale[o] / sqrt(128),
// so the hot path is two plain B^T GEMMs with a fused gelu epilogue.
// R7 (= R6 resubmit + swizzle fix): 256x256 8-phase template (T2+T3/T4+T5):
// BK=64, 8 waves (2Mx4N), 128 KiB LDS dbuf, mfma_f32_16x16x32_bf16,
// 4 phases/K-tile, counted vmcnt(4) once per K-tile (never 0 in steady state).
// Swizzle upgraded 1-bit -> 3-bit: element col ^= (row&7)*8 (G4 recipe for
// 128B-stride rows). ds_read slot = (q|ks<<2)^(lane&7): every 8-lane phase
// covers all 8 16B slots -> conflict-free. ks offsets pre-XOR'd (carry hazard).
// Staging: global col pre-swizzled 8*((lane&7)^(lane>>3)); LDS dest linear.
// Half-tile staging stream per K-tile: [A0, B0, A1, B1]; iteration t stages
//   ph1:(t+1,A1)->buf e  ph2:(t+1,B1)->buf e  ph3:(t+2,A0)->buf d  ph4:(t+2,B0)->buf d
// WAR-safe: As[d][0]/Bs[d][0] last ds_read in ph2; same-buffer stages only
// issue after ph2's closing barrier. vmcnt(4) at ph4 => K-tile t+1 landed.
// ---------------------------------------------------------------------------

typedef __attribute__((ext_vector_type(8))) short short8;
typedef __attribute__((ext_vector_type(4))) float floatx4;

#define GLOAD(gp, lp)                                                               \
  __builtin_amdgcn_global_load_lds(                                                 \
      (const __attribute__((address_space(1))) unsigned int*)(gp),                  \
      (__attribute__((address_space(3))) unsigned int*)(lp), 16, 0, 0)

#define SCHED0() __builtin_amdgcn_sched_barrier(0)
#define BARRIER()                                  \
  do {                                             \
    SCHED0();                                      \
    asm volatile("" ::: "memory");                 \
    __builtin_amdgcn_s_barrier();                  \
    asm volatile("" ::: "memory");                 \
    SCHED0();                                      \
  } while (0)
#define LGKM0()                                              \
  do {                                                       \
    asm volatile("s_waitcnt lgkmcnt(0)" ::: "memory");       \
    SCHED0();                                                \
  } while (0)
#define LGKM_HINT() asm volatile("s_waitcnt lgkmcnt(8)" ::: "memory")
#define VMCNT(n)                                             \
  do {                                                       \
    asm volatile("s_waitcnt vmcnt(" #n ")" ::: "memory");    \
    SCHED0();                                                \
  } while (0)

__device__ __forceinline__ float bf2f(unsigned int u16) {
    union { unsigned int i; float f; } v;
    v.i = u16 << 16;
    return v.f;
}

__device__ __forceinline__ unsigned short f2bf(float f) {
    union { float f; unsigned int i; } v;
    v.f = f;
    unsigned int r = v.i + 0x7FFFu + ((v.i >> 16) & 1u);  // RTNE
    return (unsigned short)(r >> 16);
}

// tanh-approx gelu, matching jax.nn.gelu(approximate=True).
__device__ __forceinline__ float gelu_tanh(float x) {
    float u = 0.7978845608028654f * (x + 0.044715f * x * x * x);
    float e = __expf(2.0f * u);
    float t = 1.0f - 2.0f / (e + 1.0f);
    return 0.5f * x * (1.0f + t);
}

// dtype flag: signs[0] is exactly +-1. f32 word0 low16 == 0; bf16 != 0.
__device__ __forceinline__ int dtype_flag(const void* signs_raw) {
    return ((*(const unsigned int*)signs_raw) & 0xFFFFu) ? 1 : 0;
}

// ---------------------------------------------------------------------------
// FWHT of one 128-block of one weight row (device helper).
// ---------------------------------------------------------------------------
__device__ __forceinline__ void fwht_block(const void* wq, const void* scale,
                                           const void* signs, unsigned short* out,
                                           int fl, int D, int nblk, int gwave, int lane) {
    int o = gwave / nblk;
    int blk = gwave - o * nblk;
    size_t base = (size_t)o * D + (size_t)blk * 128;

    float v0, v1, s0, s1, sc;
    if (fl) {  // bf16 inputs
        unsigned int p = ((const unsigned int*)((const unsigned short*)wq + base))[lane];
        v0 = bf2f(p & 0xffffu);
        v1 = bf2f(p >> 16);
        unsigned int sp =
            ((const unsigned int*)((const unsigned short*)signs + (size_t)blk * 128))[lane];
        s0 = bf2f(sp & 0xffffu);
        s1 = bf2f(sp >> 16);
        sc = bf2f(((const unsigned short*)scale)[o]);
    } else {  // f32 inputs
        const float* wf = (const float*)wq + base;
        v0 = wf[2 * lane];
        v1 = wf[2 * lane + 1];
        const float* sf = (const float*)signs + (size_t)blk * 128;
        s0 = sf[2 * lane];
        s1 = sf[2 * lane + 1];
        sc = ((const float*)scale)[o];
    }

    {
        float a = v0, b = v1;
        v0 = a + b;
        v1 = a - b;
    }
#pragma unroll
    for (int m = 1; m <= 32; m <<= 1) {
        float p0 = __shfl_xor(v0, m, 64);
        float p1 = __shfl_xor(v1, m, 64);
        if (lane & m) {
            v0 = p0 - v0;
            v1 = p1 - v1;
        } else {
            v0 = v0 + p0;
            v1 = v1 + p1;
        }
    }

    sc *= 0.08838834764831845f;  // 1/sqrt(128)
    unsigned short o0 = f2bf(v0 * sc * s0);
    unsigned short o1 = f2bf(v1 * sc * s1);
    ((unsigned int*)(out + base))[lane] = (unsigned int)o0 | ((unsigned int)o1 << 16);
}

// ---------------------------------------------------------------------------
// Merged prep: [0,nbX) convert x -> bf16; [nbX,nbX+nbW) FWHT w_up;
// [nbX+nbW, nbX+2*nbW) FWHT w_dn. 256 threads/block.
// ---------------------------------------------------------------------------
__global__ __launch_bounds__(256) void prep(const void* __restrict__ x,
                                            const void* __restrict__ up_wq,
                                            const void* __restrict__ up_scale,
                                            const void* __restrict__ dn_wq,
                                            const void* __restrict__ dn_scale,
                                            const void* __restrict__ up_signs,
                                            const void* __restrict__ dn_signs,
                                            unsigned short* __restrict__ x_bf,
                                            unsigned short* __restrict__ w_up,
                                            unsigned short* __restrict__ w_dn,
                                            int nbX, int nbW, int D_IN, int D_MID) {
    const int fl = dtype_flag(up_signs);
    const int bid = blockIdx.x;
    if (bid < nbX) {
        size_t e = ((size_t)bid * 256 + threadIdx.x) * 8;
        if (fl) {
            *(uint4*)(x_bf + e) = *(const uint4*)((const unsigned short*)x + e);
        } else {
            const float* xf = (const float*)x + e;
            uint4 r;
            r.x = (unsigned)f2bf(xf[0]) | ((unsigned)f2bf(xf[1]) << 16);
            r.y = (unsigned)f2bf(xf[2]) | ((unsigned)f2bf(xf[3]) << 16);
            r.z = (unsigned)f2bf(xf[4]) | ((unsigned)f2bf(xf[5]) << 16);
            r.w = (unsigned)f2bf(xf[6]) | ((unsigned)f2bf(xf[7]) << 16);
            *(uint4*)(x_bf + e) = r;
        }
    } else if (bid < nbX + nbW) {
        int gwave = (bid - nbX) * 4 + (threadIdx.x >> 6);
        fwht_block(up_wq, up_scale, up_signs, w_up, fl, D_IN, D_IN / 128, gwave,
                   threadIdx.x & 63);
    } else {
        int gwave = (bid - nbX - nbW) * 4 + (threadIdx.x >> 6);
        fwht_block(dn_wq, dn_scale, dn_signs, w_dn, fl, D_MID, D_MID / 128, gwave,
                   threadIdx.x & 63);
    }
}

// ---------------------------------------------------------------------------
// 256x256 8-phase B^T GEMM helpers
// ---------------------------------------------------------------------------
__device__ __forceinline__ void stage_half(const unsigned short* g, unsigned short* l,
                                           size_t goff, int K, int ldsW) {
    GLOAD(g + goff, l + ldsW);
    GLOAD(g + goff + (size_t)8 * K, l + ldsW + 512);
}

// o0/o1 = fully swizzled (row + kstep) element offsets for ks=0/1; f adds rows.
__device__ __forceinline__ void ld_frags(short8 (&fr)[2][2], const unsigned short* base,
                                         int o0, int o1) {
#pragma unroll
    for (int f = 0; f < 2; ++f) {
        fr[f][0] = *(const short8*)(base + f * 1024 + o0);
        fr[f][1] = *(const short8*)(base + f * 1024 + o1);
    }
}

__device__ __forceinline__ void ld_frags4(short8 (&fr)[4][2], const unsigned short* base,
                                          int o0, int o1) {
#pragma unroll
    for (int f = 0; f < 4; ++f) {
        fr[f][0] = *(const short8*)(base + f * 1024 + o0);
        fr[f][1] = *(const short8*)(base + f * 1024 + o1);
    }
}

__device__ __forceinline__ void mfma_quad(floatx4 (&acc)[8][4], const short8 (&ar)[4][2],
                                          const short8 (&br)[2][2], int MO, int NO) {
    __builtin_amdgcn_s_setprio(1);
#pragma unroll
    for (int ks = 0; ks < 2; ++ks)
#pragma unroll
        for (int fm = 0; fm < 4; ++fm)
#pragma unroll
            for (int fn = 0; fn < 2; ++fn)
                acc[MO + fm][NO + fn] = __builtin_amdgcn_mfma_f32_16x16x32_bf16(
                    ar[fm][ks], br[fn][ks], acc[MO + fm][NO + fn], 0, 0, 0);
    __builtin_amdgcn_s_setprio(0);
}

// ---------------------------------------------------------------------------
// B^T GEMM: C[M,N] = A[M,K] @ B[N,K]^T, bf16 in, fp32 accum.
// 256x256 tile, BK=64, 8 waves (wm=wave>>2 in {0,1}, wn=wave&3 in {0..3}),
// per-wave output 128x64, 16x16x32 MFMA (C/D: col=lane&15, row=(lane>>4)*4+reg).
// LDS: [dbuf][half(128 rows)][128x64] for A and B. Swizzle: element
// col ^= (row&7)*8, realized as inverse-swizzled GLOBAL source (gload_lds
// dest is linear base+lane*16) + swizzled ds_read offsets.
// ---------------------------------------------------------------------------
template <int ACT, int OUT_DYN>
__global__ __launch_bounds__(512, 2) void gemm256(const unsigned short* __restrict__ A,
                                                  const unsigned short* __restrict__ B,
                                                  void* __restrict__ C,
                                                  const void* __restrict__ sflag,
                                                  int N, int K, int rowOff,
                                                  int NTn, int GM, int strip) {
    __shared__ __align__(16) unsigned short As[2][2][128 * 64];
    __shared__ __align__(16) unsigned short Bs[2][2][128 * 64];

    // ---- block swizzle: XCD (flat&7) owns an M-strip; GM-panel sweep ----
    int flat = blockIdx.x;
    int mt, nt;
    if (strip > 0) {
        int xcd = flat & 7;
        int s = flat >> 3;
        int perPanel = GM * NTn;
        int p = s / perPanel;
        int r = s - p * perPanel;
        nt = r / GM;
        mt = xcd * strip + p * GM + (r - nt * GM);
    } else {
        int perPanel = GM * NTn;
        int p = flat / perPanel;
        int r = flat - p * perPanel;
        nt = r / GM;
        mt = p * GM + (r - nt * GM);
    }
    const int tileM = mt * 256, tileN = nt * 256;

    const int tid = threadIdx.x;
    const int lane = tid & 63;
    const int wave = tid >> 6;
    const int wm = wave >> 2;  // 0..1 -> A half
    const int wn = wave & 3;   // 0..3 -> 64-col slice; B half = wn>>1

    int fl = 1;
    if (OUT_DYN) {
        fl = dtype_flag(sflag);
        asm volatile("" ::"v"(fl));  // materialize now -> clean vmcnt before staging
    }

    // staging: wave w covers rows w*16..w*16+15 of a 128-row half-tile.
    // lane l, gload i: LDS linear row = w*16 + i*8 + (l>>3), col (l&7)*8.
    // content pre-swizzled: global col = ((l&7) ^ (row&7))*8; row&7 = l>>3.
    const int gcol = (((lane & 7) ^ (lane >> 3)) * 8);  // elements
    const size_t goff = (size_t)(wave * 16 + (lane >> 3)) * K + gcol;
    const int ldsW = wave * 1024;  // elements

    // ds_read: row = f*16 + (lane&15) (row&7 = lane&7), kcol = ks*32+(lane>>4)*8.
    // swizzled col = (ks*32 | (lane>>4)*8) ^ ((lane&7)*8) -- pre-XOR'd per ks
    // (XOR bits overlap ks*32, cannot add after). slot=(q|ks<<2)^(lane&7):
    // each 8 consecutive lanes cover all 8 16B slots -> conflict-free b128.
    const int sw = (lane & 7) * 8;
    const int o0 = (lane & 15) * 64 + (((lane >> 4) * 8) ^ sw);
    const int o1 = (lane & 15) * 64 + ((32 | ((lane >> 4) * 8)) ^ sw);

    const unsigned short* Ab = A + (size_t)tileM * K;
    const unsigned short* Bb = B + (size_t)tileN * K;
    const int NTt = K >> 6;

    floatx4 acc[8][4];
#pragma unroll
    for (int i = 0; i < 8; ++i)
#pragma unroll
        for (int j = 0; j < 4; ++j) acc[i][j] = (floatx4)0.0f;

    // ---- prologue: stream [A0,B0,A1,B1] -- K-tile0 (4 halves) + K-tile1 (A0,B0)
    stage_half(Ab, &As[0][0][0], goff, K, ldsW);                      // (0,A0)
    stage_half(Bb, &Bs[0][0][0], goff, K, ldsW);                      // (0,B0)
    stage_half(Ab + (size_t)128 * K, &As[0][1][0], goff, K, ldsW);    // (0,A1)
    stage_half(Bb + (size_t)128 * K, &Bs[0][1][0], goff, K, ldsW);    // (0,B1)
    if (NTt > 1) {
        stage_half(Ab + 64, &As[1][0][0], goff, K, ldsW);             // (1,A0)
        stage_half(Bb + 64, &Bs[1][0][0], goff, K, ldsW);             // (1,B0)
        VMCNT(4);  // K-tile 0 fully landed; (1,A0),(1,B0) may be in flight
    } else {
        VMCNT(0);
    }
    BARRIER();

    short8 ar0[4][2], ar1[4][2], br0[2][2], br1[2][2];

    for (int t = 0; t < NTt; ++t) {
        const int d = t & 1, e = d ^ 1;
        const unsigned short* Ah = &As[d][wm][0];
        const unsigned short* Bh = &Bs[d][wn >> 1][0];
        const int bro = (wn & 1) * 64 * 64;  // wave's 64-row block within B half

        // ---- phase 1: read A(qm0)+B(qn0) [12 reads]; stage (t+1,A1) -> buf e
        ld_frags4(ar0, Ah, o0, o1);
        ld_frags(br0, Bh + bro, o0, o1);
        if (t + 1 < NTt)
            stage_half(Ab + (size_t)128 * K + (size_t)(t + 1) * 64, &As[e][1][0], goff, K,
                       ldsW);
        LGKM_HINT();
        BARRIER();
        LGKM0();
        mfma_quad(acc, ar0, br0, 0, 0);  // (qm0,qn0)
        BARRIER();

        // ---- phase 2: read A(qm1)+B(qn1) [12 reads]; stage (t+1,B1) -> buf e
        ld_frags4(ar1, Ah + 64 * 64, o0, o1);
        ld_frags(br1, Bh + bro + 32 * 64, o0, o1);
        if (t + 1 < NTt)
            stage_half(Bb + (size_t)128 * K + (size_t)(t + 1) * 64, &Bs[e][1][0], goff, K,
                       ldsW);
        LGKM_HINT();
        BARRIER();
        LGKM0();
        mfma_quad(acc, ar1, br0, 4, 0);  // (qm1,qn0)
        BARRIER();

        // ---- phase 3: stage (t+2,A0) -> buf d (As[d][0] last ds_read was ph2)
        if (t + 2 < NTt)
            stage_half(Ab + (size_t)(t + 2) * 64, &As[d][0][0], goff, K, ldsW);
        BARRIER();
        mfma_quad(acc, ar1, br1, 4, 2);  // (qm1,qn1)
        BARRIER();

        // ---- phase 4: stage (t+2,B0) -> buf d; counted vmcnt (K-tile t+1 ready)
        if (t + 2 < NTt) {
            stage_half(Bb + (size_t)(t + 2) * 64, &Bs[d][0][0], goff, K, ldsW);
            VMCNT(4);
        } else {
            VMCNT(0);
        }
        BARRIER();
        mfma_quad(acc, ar0, br1, 0, 2);  // (qm0,qn1)
        BARRIER();
    }

    // ---- epilogue: C/D col=lane&15, row=(lane>>4)*4+reg ----
    const int c4 = lane & 15;
    const int rg = (lane >> 4) * 4;
#pragma unroll
    for (int fm = 0; fm < 8; ++fm) {
        const int gr = tileM + wm * 128 + fm * 16 + rg;
#pragma unroll
        for (int fn = 0; fn < 4; ++fn) {
            const int gc = tileN + wn * 64 + fn * 16 + c4;
#pragma unroll
            for (int j = 0; j < 4; ++j) {
                float v = acc[fm][fn][j];
                if (ACT) v = gelu_tanh(v);
                size_t idx = (size_t)(rowOff + gr + j) * N + gc;
                if (fl)
                    ((unsigned short*)C)[idx] = f2bf(v);
                else
                    ((float*)C)[idx] = v;
            }
        }
    }
}

// largest divisor of n that is <= cap
static inline int div_le(int n, int cap) {
    for (int g = cap; g > 1; --g)
        if (n % g == 0) return g;
    return 1;
}

// ---------------------------------------------------------------------------
extern "C" void kernel_launch(void* const* d_in, const int* in_sizes, int n_in,
                              void* d_out, int out_size, void* d_ws, size_t ws_size,
                              hipStream_t stream) {
    const int T = 16384, D_IN = 1024, D_MID = 4096, D_OUT = 1024;

    // ws layout: [w_up 8MiB][w_dn 8MiB][x_bf16 32MiB][a slice ...]
    unsigned short* w_up = (unsigned short*)d_ws;
    unsigned short* w_dn = w_up + (size_t)D_MID * D_IN;
    unsigned short* x_bf = w_dn + (size_t)D_OUT * D_MID;
    unsigned short* a_buf = x_bf + (size_t)T * D_IN;

    size_t used = ((size_t)D_MID * D_IN + (size_t)D_OUT * D_MID + (size_t)T * D_IN) * 2;
    size_t avail = ws_size > used ? ws_size - used : 0;
    long tc = (long)(avail / ((size_t)D_MID * 2));
    tc = (tc / 256) * 256;
    if (tc > T) tc = T;
    if (tc < 256) tc = 256;  // last resort; needs ws_size >= ~50 MiB
    const int Tc = (int)tc;

    {
        int nbX = (T * D_IN / 8) / 256;        // 8192
        int nbW = (D_MID * (D_IN / 128)) / 4;  // 8192 (== dn wave count / 4)
        prep<<<dim3(nbX + 2 * nbW), dim3(256), 0, stream>>>(
            d_in[0], d_in[1], d_in[2], d_in[3], d_in[4], d_in[5], d_in[6], x_bf, w_up, w_dn,
            nbX, nbW, D_IN, D_MID);
    }

    for (int r0 = 0; r0 < T; r0 += Tc) {
        int Ms = (T - r0 < Tc) ? (T - r0) : Tc;
        int MT = Ms / 256;
        int strip = (MT % 8 == 0 && MT >= 8) ? MT / 8 : 0;

        // GEMM1: A-tile 512KB -> GM=4 keeps A-panel ~2MiB in XCD L2
        {
            int NTn = D_MID / 256;  // 16
            int GM = (strip > 0) ? div_le(strip, 4) : div_le(MT, 4);
            gemm256<1, 0><<<dim3(MT * NTn), dim3(512), 0, stream>>>(
                x_bf + (size_t)r0 * D_IN, w_up, a_buf, d_in[5], D_MID, D_IN, 0, NTn, GM,
                strip);
        }
        // GEMM2: A-tile 2MiB -> GM=2 keeps panel ~4MiB
        {
            int NTn = D_OUT / 256;  // 4
            int GM = (strip > 0) ? div_le(strip, 2) : div_le(MT, 2);
            gemm256<0, 1><<<dim3(MT * NTn), dim3(512), 0, stream>>>(
                a_buf, w_dn, d_out, d_in[5], D_OUT, D_MID, r0, NTn, GM, strip);
        }
    }
}